// Round 5
// baseline (470.690 us; speedup 1.0000x reference)
//
#include <hip/hip_runtime.h>
#include <math.h>

#define BB 16
#define SP1c 513
#define VV 32000
#define NROWS (BB * 512)              // 8192 blocks
#define THREADS 320                   // 8000 float4 / 320 = 25 iters exact
#define NGROUPS 64
#define GROUP_SIZE (NROWS / NGROUPS)  // 128 blocks per group

typedef float f32x4 __attribute__((ext_vector_type(4)));

static __device__ __forceinline__ f32x4 ntload4(const f32x4* p) {
    return __builtin_nontemporal_load(p);   // zero-reuse stream: bypass L2
}

// One accumulator line per group, 128B-aligned to avoid false sharing.
struct __align__(128) GroupAcc {
    unsigned long long ticks;   // fixed-point nll sum, 2^-30 quantum
    unsigned int cnt;           // valid-row count
    unsigned int done;          // blocks-finished counter for this group
};

#define UPD(M, S, v)                                                        \
    {                                                                       \
        float mx_ = fmaxf(fmaxf((v).x, (v).y), fmaxf((v).z, (v).w));        \
        float nm_ = fmaxf((M), mx_);                                        \
        (S) = (S) * __expf((M) - nm_) + __expf((v).x - nm_) +               \
              __expf((v).y - nm_) + __expf((v).z - nm_) +                   \
              __expf((v).w - nm_);                                          \
        (M) = nm_;                                                          \
    }

__global__ __launch_bounds__(THREADS) void ce_fused_kernel(
    const float* __restrict__ logits,   // (B, SP1, V) f32
    const int* __restrict__ trg,        // (B, SP1)
    const int* __restrict__ lengths,    // (B,)
    GroupAcc* __restrict__ grp,         // 64 lines, zeroed each launch
    unsigned int* __restrict__ gdone,   // own line, zeroed each launch
    float* __restrict__ out)
{
    const int blk = blockIdx.x;
    const int b = blk & 15;             // batch-interleaved: valid work
    const int s = blk >> 4;             // spreads uniformly over dispatch
    const int g = blk & (NGROUPS - 1);

    const int tgt = trg[b * SP1c + (s + 1)];
    const bool valid = (s < lengths[b]) && (tgt != 0);

    if (valid) {
        const float* rowp = logits + ((size_t)b * SP1c + (s + 1)) * VV;
        const f32x4* rp4 = reinterpret_cast<const f32x4*>(rowp);

        // Target logit issued first: HBM latency hides under the stream.
        const float xt = rowp[tgt];

        float m0 = -1e30f, m1 = -1e30f, m2 = -1e30f, m3 = -1e30f, m4 = -1e30f;
        float s0 = 0.f, s1 = 0.f, s2 = 0.f, s3 = 0.f, s4 = 0.f;

        int i = threadIdx.x;
        #pragma unroll
        for (int r = 0; r < 5; ++r) {
            f32x4 v0 = ntload4(&rp4[i]);
            f32x4 v1 = ntload4(&rp4[i + THREADS]);
            f32x4 v2 = ntload4(&rp4[i + 2 * THREADS]);
            f32x4 v3 = ntload4(&rp4[i + 3 * THREADS]);
            f32x4 v4 = ntload4(&rp4[i + 4 * THREADS]);
            UPD(m0, s0, v0)
            UPD(m1, s1, v1)
            UPD(m2, s2, v2)
            UPD(m3, s3, v3)
            UPD(m4, s4, v4)
            i += 5 * THREADS;
        }

        float M = m0, Ssum = s0;
        {
            float nm = fmaxf(M, m1); Ssum = Ssum * __expf(M - nm) + s1 * __expf(m1 - nm); M = nm;
            nm = fmaxf(M, m2); Ssum = Ssum * __expf(M - nm) + s2 * __expf(m2 - nm); M = nm;
            nm = fmaxf(M, m3); Ssum = Ssum * __expf(M - nm) + s3 * __expf(m3 - nm); M = nm;
            nm = fmaxf(M, m4); Ssum = Ssum * __expf(M - nm) + s4 * __expf(m4 - nm); M = nm;
        }

        #pragma unroll
        for (int off = 32; off > 0; off >>= 1) {
            float om = __shfl_down(M, off);
            float os = __shfl_down(Ssum, off);
            float nm = fmaxf(M, om);
            Ssum = Ssum * __expf(M - nm) + os * __expf(om - nm);
            M = nm;
        }

        __shared__ float sm[THREADS / 64];
        __shared__ float ss[THREADS / 64];
        const int wave = threadIdx.x >> 6;
        const int lane = threadIdx.x & 63;
        if (lane == 0) { sm[wave] = M; ss[wave] = Ssum; }
        __syncthreads();

        if (threadIdx.x == 0) {
            float Mt = sm[0];
            float St = ss[0];
            #pragma unroll
            for (int w = 1; w < THREADS / 64; ++w) {
                float nm = fmaxf(Mt, sm[w]);
                St = St * __expf(Mt - nm) + ss[w] * __expf(sm[w] - nm);
                Mt = nm;
            }
            const float nll = (Mt + __logf(St)) - xt;   // >= 0 (mod rounding)
            const long long ticks = llrintf(nll * 1073741824.0f);
            atomicAdd(&grp[g].ticks, (unsigned long long)ticks);  // int = deterministic
            atomicAdd(&grp[g].cnt, 1u);
        }
    }

    // Hierarchical completion: 128 RMWs per group line, 64 to the global line.
    __shared__ int fin;
    if (threadIdx.x == 0) {
        fin = 0;
        __threadfence();   // release our adds before done++
        unsigned int gd = atomicAdd(&grp[g].done, 1u);
        if (gd == GROUP_SIZE - 1) {
            unsigned int t = atomicAdd(gdone, 1u);
            if (t == NGROUPS - 1) fin = 1;
        }
    }
    __syncthreads();

    if (fin) {
        __threadfence();   // acquire all groups' adds
        if (threadIdx.x < 64) {
            unsigned long long tk = atomicAdd(&grp[threadIdx.x].ticks, 0ULL);
            unsigned int c = atomicAdd(&grp[threadIdx.x].cnt, 0u);
            #pragma unroll
            for (int off = 32; off > 0; off >>= 1) {
                tk += __shfl_down(tk, off);
                c += __shfl_down(c, off);
            }
            if (threadIdx.x == 0) {
                double loss = ((double)(long long)tk * (1.0 / 1073741824.0)) /
                              (double)(c > 0u ? c : 1u);
                out[0] = (float)loss;
            }
        }
    }
}

extern "C" void kernel_launch(void* const* d_in, const int* in_sizes, int n_in,
                              void* d_out, int out_size, void* d_ws, size_t ws_size,
                              hipStream_t stream) {
    const float* logits  = (const float*)d_in[0];
    const int*   trg     = (const int*)d_in[1];
    const int*   lengths = (const int*)d_in[2];

    GroupAcc* grp = (GroupAcc*)d_ws;
    unsigned int* gdone = (unsigned int*)((char*)d_ws + NGROUPS * sizeof(GroupAcc));

    hipMemsetAsync(d_ws, 0, NGROUPS * sizeof(GroupAcc) + 128, stream);
    ce_fused_kernel<<<NROWS, THREADS, 0, stream>>>(logits, trg, lengths, grp,
                                                   gdone, (float*)d_out);
}

// Round 6
// 77.213 us; speedup vs baseline: 6.0960x; 6.0960x over previous
//
#include <hip/hip_runtime.h>
#include <math.h>

#define BB 16
#define SP1c 513
#define VV 32000
#define NROWS (BB * 512)      // 8192
#define THREADS 320           // 8000 float4 / 320 = 25 iterations, exact fit
#define RTHREADS 256

typedef float f32x4 __attribute__((ext_vector_type(4)));
typedef float f32x2 __attribute__((ext_vector_type(2)));

static __device__ __forceinline__ f32x4 ntload4(const f32x4* p) {
    return __builtin_nontemporal_load(p);   // zero-reuse stream: bypass L2
}

#define UPD(M, S, v)                                                        \
    {                                                                       \
        float mx_ = fmaxf(fmaxf((v).x, (v).y), fmaxf((v).z, (v).w));        \
        float nm_ = fmaxf((M), mx_);                                        \
        (S) = (S) * __expf((M) - nm_) + __expf((v).x - nm_) +               \
              __expf((v).y - nm_) + __expf((v).z - nm_) +                   \
              __expf((v).w - nm_);                                          \
        (M) = nm_;                                                          \
    }

// One block per (b, s) row. Early-exit masked rows (~50%); 5 independent
// online-softmax accumulators break the exp-rescale dependency chain.
// NO atomics, NO fences: R2/R5 showed per-block device-scope fencing costs
// ~400 us on this chip (8 XCDs, agent-scope release serializes ~50ns each).
__global__ __launch_bounds__(THREADS) void ce_row_kernel(
    const float* __restrict__ logits,   // (B, SP1, V) f32
    const int* __restrict__ trg,        // (B, SP1)
    const int* __restrict__ lengths,    // (B,)
    f32x2* __restrict__ row_out)        // (NROWS,) {nll, valid}
{
    const int row = blockIdx.x;
    const int b = row >> 9;
    const int s = row & 511;

    const int tgt = trg[b * SP1c + (s + 1)];
    const bool valid = (s < lengths[b]) && (tgt != 0);
    if (!valid) {
        if (threadIdx.x == 0) row_out[row] = f32x2{0.0f, 0.0f};
        return;
    }

    const float* rowp = logits + ((size_t)b * SP1c + (s + 1)) * VV;
    const f32x4* rp4 = reinterpret_cast<const f32x4*>(rowp);

    // Target logit issued first: its HBM latency hides under the stream.
    const float xt = rowp[tgt];

    float m0 = -1e30f, m1 = -1e30f, m2 = -1e30f, m3 = -1e30f, m4 = -1e30f;
    float s0 = 0.f, s1 = 0.f, s2 = 0.f, s3 = 0.f, s4 = 0.f;

    int i = threadIdx.x;
    #pragma unroll
    for (int r = 0; r < 5; ++r) {
        f32x4 v0 = ntload4(&rp4[i]);
        f32x4 v1 = ntload4(&rp4[i + THREADS]);
        f32x4 v2 = ntload4(&rp4[i + 2 * THREADS]);
        f32x4 v3 = ntload4(&rp4[i + 3 * THREADS]);
        f32x4 v4 = ntload4(&rp4[i + 4 * THREADS]);
        UPD(m0, s0, v0)
        UPD(m1, s1, v1)
        UPD(m2, s2, v2)
        UPD(m3, s3, v3)
        UPD(m4, s4, v4)
        i += 5 * THREADS;
    }

    // Merge 5 accumulators.
    float M = m0, Ssum = s0;
    {
        float nm = fmaxf(M, m1); Ssum = Ssum * __expf(M - nm) + s1 * __expf(m1 - nm); M = nm;
        nm = fmaxf(M, m2); Ssum = Ssum * __expf(M - nm) + s2 * __expf(m2 - nm); M = nm;
        nm = fmaxf(M, m3); Ssum = Ssum * __expf(M - nm) + s3 * __expf(m3 - nm); M = nm;
        nm = fmaxf(M, m4); Ssum = Ssum * __expf(M - nm) + s4 * __expf(m4 - nm); M = nm;
    }

    // Wave (64-lane) reduction.
    #pragma unroll
    for (int off = 32; off > 0; off >>= 1) {
        float om = __shfl_down(M, off);
        float os = __shfl_down(Ssum, off);
        float nm = fmaxf(M, om);
        Ssum = Ssum * __expf(M - nm) + os * __expf(om - nm);
        M = nm;
    }

    // Cross-wave reduction (5 waves).
    __shared__ float sm[THREADS / 64];
    __shared__ float ss[THREADS / 64];
    const int wave = threadIdx.x >> 6;
    const int lane = threadIdx.x & 63;
    if (lane == 0) { sm[wave] = M; ss[wave] = Ssum; }
    __syncthreads();

    if (threadIdx.x == 0) {
        float Mt = sm[0];
        float St = ss[0];
        #pragma unroll
        for (int w = 1; w < THREADS / 64; ++w) {
            float nm = fmaxf(Mt, sm[w]);
            St = St * __expf(Mt - nm) + ss[w] * __expf(sm[w] - nm);
            Mt = nm;
        }
        row_out[row] = f32x2{(Mt + __logf(St)) - xt, 1.0f};
    }
}

// Deterministic final reduction: single block, fixed order, one contiguous
// 64KB stream of (nll, cnt) pairs.
__global__ __launch_bounds__(RTHREADS) void ce_final_kernel(
    const f32x2* __restrict__ row_out,
    float* __restrict__ out)
{
    const f32x4* r4 = reinterpret_cast<const f32x4*>(row_out);  // 2 rows/load
    float s = 0.0f;
    float n = 0.0f;   // exact integer count up to 2^24
    for (int i = threadIdx.x; i < NROWS / 2; i += RTHREADS) {
        f32x4 v = r4[i];
        s += v.x + v.z;
        n += v.y + v.w;
    }
    #pragma unroll
    for (int off = 32; off > 0; off >>= 1) {
        s += __shfl_down(s, off);
        n += __shfl_down(n, off);
    }
    __shared__ float sl[RTHREADS / 64];
    __shared__ float sn[RTHREADS / 64];
    const int wave = threadIdx.x >> 6;
    const int lane = threadIdx.x & 63;
    if (lane == 0) { sl[wave] = s; sn[wave] = n; }
    __syncthreads();
    if (threadIdx.x == 0) {
        float ts = 0.0f, tn = 0.0f;
        #pragma unroll
        for (int w = 0; w < RTHREADS / 64; ++w) { ts += sl[w]; tn += sn[w]; }
        out[0] = ts / fmaxf(tn, 1.0f);
    }
}

extern "C" void kernel_launch(void* const* d_in, const int* in_sizes, int n_in,
                              void* d_out, int out_size, void* d_ws, size_t ws_size,
                              hipStream_t stream) {
    const float* logits  = (const float*)d_in[0];
    const int*   trg     = (const int*)d_in[1];
    const int*   lengths = (const int*)d_in[2];

    f32x2* row_out = (f32x2*)d_ws;   // 64 KB

    ce_row_kernel<<<NROWS, THREADS, 0, stream>>>(logits, trg, lengths, row_out);
    ce_final_kernel<<<1, RTHREADS, 0, stream>>>(row_out, (float*)d_out);
}